// Round 12
// baseline (107909.839 us; speedup 1.0000x reference)
//
#include <hip/hip_runtime.h>

#define T_STEPS 8192
#define HID 1024
#define G4 4096
#define NBLK 128    // blocks per layer; grid = 256
#define NTHR 512    // 8 waves
#define NSLOT 16    // rotation depth

typedef unsigned int uint32;

// Global comm (memset 0xFF each launch): tagged fp32 h values.
// Slot s = t & 15; tag = (t>>4) & 15 in the 4 low mantissa bits.
// Safety: intra-cohort lag <=1 step (publish t requires full gather of t-1);
// cross-cohort: L0 publish at t overwrites h0_{t-16}; guard = hB[t-16]
// complete (L1 finished step t-16 => consumed global h0_{t-16}). Each wave
// verifies this ITSELF when the cached bpA is stale — no cross-wave wait.
struct Comm {
    uint32 hA[NSLOT][HID];   // layer-0 h
    uint32 hB[NSLOT][HID];   // layer-1 h
};

#define LD_AG  __HIP_MEMORY_SCOPE_AGENT
#define LD_WG  __HIP_MEMORY_SCOPE_WORKGROUP

__device__ inline float sigm(float x) { return 1.0f / (1.0f + __expf(-x)); }
__device__ inline float tanh_f(float x) {
    x = fminf(fmaxf(x, -15.f), 15.f);
    float e = __expf(-2.0f * x);
    return (1.0f - e) / (1.0f + e);
}
__device__ inline uint32 tagf(float f, uint32 tg) {
    union { float f; uint32 u; } a; a.f = f;
    return (a.u & ~15u) | tg;
}

// out[m][perm(n)] = A[m][:] . W[n][:] + bi[n] + bh[n]
// perm: j = n&1023, gate = n>>10; idx = (j>>3)*32 + (j&7)*4 + gate
__global__ __launch_bounds__(256)
void gemm_xg(const float* __restrict__ A, const float* __restrict__ W,
             const float* __restrict__ bi, const float* __restrict__ bh,
             float* __restrict__ out)
{
    __shared__ float As[16][65];
    __shared__ float Bs[16][65];
    const int tid = threadIdx.x;
    const int m0 = blockIdx.y * 64, n0 = blockIdx.x * 64;
    const int tm = tid & 15, tn = tid >> 4;
    const int row = tid >> 2, q = tid & 3;
    float acc[4][4] = {{0.f}};
    for (int k0 = 0; k0 < HID; k0 += 16) {
        float4 a = *(const float4*)(A + (size_t)(m0 + row) * HID + k0 + q * 4);
        float4 b = *(const float4*)(W + (size_t)(n0 + row) * HID + k0 + q * 4);
        __syncthreads();
        As[q*4+0][row] = a.x; As[q*4+1][row] = a.y; As[q*4+2][row] = a.z; As[q*4+3][row] = a.w;
        Bs[q*4+0][row] = b.x; Bs[q*4+1][row] = b.y; Bs[q*4+2][row] = b.z; Bs[q*4+3][row] = b.w;
        __syncthreads();
#pragma unroll
        for (int kk = 0; kk < 16; ++kk) {
            float av[4], bv[4];
#pragma unroll
            for (int i = 0; i < 4; ++i) { av[i] = As[kk][tm*4+i]; bv[i] = Bs[kk][tn*4+i]; }
#pragma unroll
            for (int i = 0; i < 4; ++i)
#pragma unroll
                for (int j = 0; j < 4; ++j) acc[i][j] += av[i] * bv[j];
        }
    }
#pragma unroll
    for (int i = 0; i < 4; ++i) {
        int m = m0 + tm * 4 + i;
#pragma unroll
        for (int j = 0; j < 4; ++j) {
            int n = n0 + tn * 4 + j;
            float v = acc[i][j] + bi[n] + bh[n];
            int jd = n & (HID - 1), gate = n >> 10;
            out[(size_t)m * G4 + (jd >> 3) * 32 + (jd & 7) * 4 + gate] = v;
        }
    }
}

// Detect one 256-word quarter (4 words/lane): spin until all tags match.
__device__ inline void detect4(const uint32* __restrict__ buf, uint32 tg,
                               int lane, uint32 v[4])
{
    for (;;) {
        bool ok = true;
#pragma unroll
        for (int r = 0; r < 4; ++r)
            v[r] = __hip_atomic_load(&buf[r * 64 + lane], __ATOMIC_RELAXED, LD_AG);
#pragma unroll
        for (int r = 0; r < 4; ++r) ok &= ((v[r] & 15u) == tg);
        if (__all(ok)) break;
    }
}

// One-shot full-vector window tag scan: true iff every word's tag is within
// [tg, tg+8) mod 16 (current value or a later rewrite => step complete).
__device__ inline bool try_scan16(const uint32* __restrict__ buf, uint32 tg, int lane)
{
    uint32 v[16]; bool ok = true;
#pragma unroll
    for (int r = 0; r < 16; ++r)
        v[r] = __hip_atomic_load(&buf[r * 64 + lane], __ATOMIC_RELAXED, LD_AG);
#pragma unroll
    for (int r = 0; r < 16; ++r) ok &= (((v[r] & 15u) - tg) & 15u) < 8u;
    return __all(ok);
}

// Fused 2-layer persistent LSTM; bulk-synchronous, ONE barrier per step.
// Blocks 0..127 = layer 0 (xg precomputed); 128..255 = layer 1
// (W_ih1 slice in 64 VGPRs/thread, W_hh1 slice in LDS). Each wave owns 1 h.
__global__ __launch_bounds__(NTHR)
void lstm_fused(const float* __restrict__ Whh0, const float* __restrict__ xg,
                const float* __restrict__ Wih1, const float* __restrict__ Whh1,
                const float* __restrict__ bih1, const float* __restrict__ bhh1,
                float* __restrict__ outF, Comm* __restrict__ cm)
{
    __shared__ float Wl[32 * HID];     // 131 KB: rows [wave*4+gate][1024]
    __shared__ float hlA[2][HID];      // parity double-buffer
    __shared__ float hlB[2][HID];
    __shared__ int bpA;
    const int blk = blockIdx.x, tid = threadIdx.x;
    const int wave = tid >> 6, lane = tid & 63;
    const int kb = (blk < NBLK) ? blk : blk - NBLK;
    const bool isL0 = (blk < NBLK);

    {
        const float* Wsrc = isL0 ? Whh0 : Whh1;
#pragma unroll
        for (int i = 0; i < 16; ++i) {
            int l = i * NTHR + tid;
            int r = l >> 8, c = l & 255;
            int w = r >> 2, g = r & 3;
            ((float4*)(Wl + r * HID))[c] =
                ((const float4*)(Wsrc + (size_t)(g * HID + 8 * kb + w) * HID))[c];
        }
    }
    for (int i = tid; i < HID; i += NTHR) {
        hlA[0][i] = 0.f; hlA[1][i] = 0.f; hlB[0][i] = 0.f; hlB[1][i] = 0.f;
    }
    if (tid == 0) bpA = -1;
    __syncthreads();

    if (isL0) {
        // ---------------- layer 0 ----------------
        const int k = kb;
        float c_state = 0.f;
        float nx0 = 0.f, nx1 = 0.f, nx2 = 0.f, nx3 = 0.f;
        if (lane == 0) {
            const float* xp = xg + k * 32 + wave * 4;
            nx0 = xp[0]; nx1 = xp[1]; nx2 = xp[2]; nx3 = xp[3];
        }
        int bp_next = 0;   // wave4's proactive scan cursor (wave-uniform)

        for (int t = 0; t < T_STEPS; ++t) {
            const int pm = (t - 1) & 1;   // parity holding h0_{t-1}
            float x0 = nx0, x1 = nx1, x2 = nx2, x3 = nx3;
            if (lane == 0 && t + 1 < T_STEPS) {
                const float* xp = xg + (size_t)(t + 1) * G4 + k * 32 + wave * 4;
                nx0 = xp[0]; nx1 = xp[1]; nx2 = xp[2]; nx3 = xp[3];
            }
            float a0 = 0.f, a1 = 0.f, a2 = 0.f, a3 = 0.f;
            const float* wb = Wl + wave * 4 * HID;
#pragma unroll 4
            for (int u = 0; u < 16; ++u) {
                float hv = hlA[pm][u * 64 + lane];
                a0 += wb[0 * HID + u * 64 + lane] * hv;
                a1 += wb[1 * HID + u * 64 + lane] * hv;
                a2 += wb[2 * HID + u * 64 + lane] * hv;
                a3 += wb[3 * HID + u * 64 + lane] * hv;
            }
#pragma unroll
            for (int off = 32; off > 0; off >>= 1) {
                a0 += __shfl_xor(a0, off, 64);
                a1 += __shfl_xor(a1, off, 64);
                a2 += __shfl_xor(a2, off, 64);
                a3 += __shfl_xor(a3, off, 64);
            }
            // cross-cohort overwrite guard, SELF-SERVICE (deadlock-free):
            // fast path = cached bpA; slow path = this wave scans hB[t-16]
            // itself. The condition depends only on layer-1 progress.
            if (t >= 16 &&
                __hip_atomic_load(&bpA, __ATOMIC_RELAXED, LD_WG) < t - 16) {
                const int s = t - 16;
                while (!try_scan16((const uint32*)cm->hB[s & 15],
                                   (s >> 4) & 15, lane)) {}
            }
            if (lane == 0) {
                float ig = sigm(x0 + a0);
                float fg = sigm(x1 + a1);
                float gg = tanh_f(x2 + a2);
                float og = sigm(x3 + a3);
                c_state = fg * c_state + ig * gg;
                float h = og * tanh_f(c_state);
                __hip_atomic_store(&cm->hA[t & 15][8 * k + wave],
                                   tagf(h, (t >> 4) & 15), __ATOMIC_RELAXED, LD_AG);
            }
            if (t == T_STEPS - 1) break;
            // poll starts immediately after own publish — no barrier first;
            // forwards into the OTHER parity, safe w.r.t. this step's reads.
            if (wave < 4) {
                uint32 v[4];
                detect4((const uint32*)cm->hA[t & 15] + wave * 256,
                        (t >> 4) & 15, lane, v);
                float* dst = hlA[t & 1] + wave * 256;
#pragma unroll
                for (int r = 0; r < 4; ++r) {
                    union { uint32 u; float f; } c; c.u = v[r];
                    dst[r * 64 + lane] = c.f;
                }
            } else if (wave == 4) {
                // proactive non-blocking bpA catch-up (fast-path freshness only)
                for (int it = 0; it < 8 && bp_next <= t; ++it) {
                    if (!try_scan16((const uint32*)cm->hB[bp_next & 15],
                                    (bp_next >> 4) & 15, lane)) break;
                    if (lane == 0)
                        __hip_atomic_store(&bpA, bp_next, __ATOMIC_RELAXED, LD_WG);
                    ++bp_next;
                }
            }
            __syncthreads();   // hlA[t&1] = h0_t ready; the only barrier
        }
    } else {
        // ---------------- layer 1 ----------------
        const int j = 8 * kb + wave;
        float wreg[4][16];
#pragma unroll
        for (int g = 0; g < 4; ++g)
#pragma unroll
            for (int u = 0; u < 16; ++u)
                wreg[g][u] = Wih1[(size_t)(g * HID + j) * HID + u * 64 + lane];
        float bia[4];
#pragma unroll
        for (int g = 0; g < 4; ++g)
            bia[g] = bih1[g * HID + j] + bhh1[g * HID + j];
        float c_state = 0.f;

        for (int t = 0; t < T_STEPS; ++t) {
            // phase A: poll h0_t (waves 0-3) and h1_{t-1} (waves 4-7)
            if (wave < 4) {
                uint32 v[4];
                detect4((const uint32*)cm->hA[t & 15] + wave * 256,
                        (t >> 4) & 15, lane, v);
                float* dst = hlA[t & 1] + wave * 256;
#pragma unroll
                for (int r = 0; r < 4; ++r) {
                    union { uint32 u; float f; } c; c.u = v[r];
                    dst[r * 64 + lane] = c.f;
                }
            } else if (t >= 1) {
                const int q = wave - 4;
                uint32 v[4];
                detect4((const uint32*)cm->hB[(t - 1) & 15] + q * 256,
                        ((t - 1) >> 4) & 15, lane, v);
                float* dst = hlB[(t - 1) & 1] + q * 256;
#pragma unroll
                for (int r = 0; r < 4; ++r) {
                    union { uint32 u; float f; } c; c.u = v[r];
                    dst[r * 64 + lane] = c.f;
                }
            }
            __syncthreads();   // the only barrier
            // phase B: compute (next step's phase A writes the other parity)
            const int pa = t & 1, pb = (t - 1) & 1;
            float a0 = 0.f, a1 = 0.f, a2 = 0.f, a3 = 0.f;
            const float* wb = Wl + wave * 4 * HID;
#pragma unroll 4
            for (int u = 0; u < 16; ++u) {
                float h0v = hlA[pa][u * 64 + lane];
                float h1v = hlB[pb][u * 64 + lane];
                a0 += wb[0 * HID + u * 64 + lane] * h1v + wreg[0][u] * h0v;
                a1 += wb[1 * HID + u * 64 + lane] * h1v + wreg[1][u] * h0v;
                a2 += wb[2 * HID + u * 64 + lane] * h1v + wreg[2][u] * h0v;
                a3 += wb[3 * HID + u * 64 + lane] * h1v + wreg[3][u] * h0v;
            }
#pragma unroll
            for (int off = 32; off > 0; off >>= 1) {
                a0 += __shfl_xor(a0, off, 64);
                a1 += __shfl_xor(a1, off, 64);
                a2 += __shfl_xor(a2, off, 64);
                a3 += __shfl_xor(a3, off, 64);
            }
            if (lane == 0) {
                float ig = sigm(bia[0] + a0);
                float fg = sigm(bia[1] + a1);
                float gg = tanh_f(bia[2] + a2);
                float og = sigm(bia[3] + a3);
                c_state = fg * c_state + ig * gg;
                float h = og * tanh_f(c_state);
                if (t == T_STEPS - 1)
                    outF[j] = h;   // untagged, full precision
                else
                    __hip_atomic_store(&cm->hB[t & 15][j],
                                       tagf(h, (t >> 4) & 15), __ATOMIC_RELAXED, LD_AG);
            }
        }
    }
}

extern "C" void kernel_launch(void* const* d_in, const int* in_sizes, int n_in,
                              void* d_out, int out_size, void* d_ws, size_t ws_size,
                              hipStream_t stream)
{
    const float* x    = (const float*)d_in[0];
    const float* Wih0 = (const float*)d_in[1];
    const float* Whh0 = (const float*)d_in[2];
    const float* bih0 = (const float*)d_in[3];
    const float* bhh0 = (const float*)d_in[4];
    const float* Wih1 = (const float*)d_in[5];
    const float* Whh1 = (const float*)d_in[6];
    const float* bih1 = (const float*)d_in[7];
    const float* bhh1 = (const float*)d_in[8];

    char* ws = (char*)d_ws;
    float* xg = (float*)ws;                     // 134217728 B
    Comm*  cm = (Comm*)(ws + 134217728);        // 131072 B

    // 0xFF fill: tag = 15; slot s first expects tag 15 only after 15 full
    // rewrites of the slot — init pattern long gone by then.
    (void)hipMemsetAsync(ws + 134217728, 0xFF, sizeof(Comm), stream);

    dim3 gg(G4 / 64, T_STEPS / 64);
    gemm_xg<<<gg, 256, 0, stream>>>(x, Wih0, bih0, bhh0, xg);
    lstm_fused<<<2 * NBLK, NTHR, 0, stream>>>(Whh0, xg, Wih1, Whh1, bih1, bhh1,
                                              (float*)d_out, cm);
}